// Round 9
// baseline (46.403 us; speedup 1.0000x reference)
//
#include <hip/hip_runtime.h>

// Chamfer NN squared distances via MFMA (f16 hi/lo emulation).
// Round-9 structure: NO LDS, NO barriers in the main loop.
//
// d(q,r) = |q|^2 + |r|^2 - 2 q.r in ONE mfma_f32_32x32x16_f16 (13 K-slots):
//   A (query row, g=0): {-2hx,-2hy,-2hz,-2hx,-2hy,-2hz,-2lx,-2ly}
//   A (query row, g=1): {-2lz, 1, 1, sh, sl, 0, 0, 0}
//   B (ref col,   g=0): { hx,  hy,  hz,  lx,  ly,  lz, hx, hy}
//   B (ref col,   g=1): { hz,  sh,  sl,  1,  1, 0, 0, 0}
// => D = squared distance (error ~1e-4 vs 0.12 threshold).
//
// R4-R8 lesson: every LDS-staged variant pinned at 33-36us (model: 10-15us);
// the invariant was the block-wide barrier drain per chunk (waves convoy,
// vmcnt/lgkmcnt(0) before s_barrier). Here a pack kernel writes A/B fragments
// to d_ws as SPLIT-HALF arrays (g=0 then g=1), so in the main kernel lanes
// 0-31 and 32-63 each read 512 B contiguous per col-block -> coalesced
// global_load_dwordx4 straight into the MFMA, loads pipelined by vmcnt with
// no barriers anywhere in the loop. B data is L2-resident (~26 TB/s demand
// < 34.5 TB/s ceiling).
//
// Grid: 1024 blocks (4 waves each, independent). 64 query rows/wave
// (2 A-frags), SPLIT=2 over refs. Partials combined via atomicMin.

typedef _Float16 v8h  __attribute__((ext_vector_type(8)));
typedef float    v16f __attribute__((ext_vector_type(16)));

constexpr int TPB   = 256;        // 4 waves
constexpr int RPW   = 64;         // rows per wave (2 A-fragments)
constexpr int RPB   = 4 * RPW;    // 256 rows per block
constexpr int SPLIT = 2;          // ref-dim split factor

__device__ __forceinline__ void split3(float x, float y, float z,
    _Float16& hx, _Float16& hy, _Float16& hz,
    _Float16& lx, _Float16& ly, _Float16& lz,
    _Float16& sh, _Float16& sl)
{
    const float s = fmaf(z, z, fmaf(y, y, x * x));
    hx = (_Float16)x; hy = (_Float16)y; hz = (_Float16)z;
    lx = (_Float16)(x - (float)hx);
    ly = (_Float16)(y - (float)hy);
    lz = (_Float16)(z - (float)hz);
    sh = (_Float16)s;
    sl = (_Float16)(s - (float)sh);
}

// ws layout (uint4 units): for each point set, 4 arrays of length n:
//   A_g0 | A_g1 | B_g0 | B_g1   (set1 at 0, set2 at 4*n1)
__global__ void pack_pts(const float* __restrict__ p1, const float* __restrict__ p2,
                         uint4* __restrict__ ws, int n1, int n2)
{
    const int gid = blockIdx.x * blockDim.x + threadIdx.x;
    if (gid >= n1 + n2) return;
    const float* src;
    int pi, n;
    uint4* base;
    if (gid < n1) { src = p1; pi = gid;      n = n1; base = ws; }
    else          { src = p2; pi = gid - n1; n = n2; base = ws + 4 * (size_t)n1; }

    const float x = src[(size_t)pi * 3 + 0];
    const float y = src[(size_t)pi * 3 + 1];
    const float z = src[(size_t)pi * 3 + 2];
    _Float16 hx, hy, hz, lx, ly, lz, sh, sl;
    split3(x, y, z, hx, hy, hz, lx, ly, lz, sh, sl);
    const _Float16 nhx = (_Float16)(-2.f * x);
    const _Float16 nhy = (_Float16)(-2.f * y);
    const _Float16 nhz = (_Float16)(-2.f * z);
    const _Float16 nlx = (_Float16)(-2.f * (float)lx);
    const _Float16 nly = (_Float16)(-2.f * (float)ly);
    const _Float16 nlz = (_Float16)(-2.f * (float)lz);
    const _Float16 one = (_Float16)1.f, zz = (_Float16)0.f;

    const v8h A0 = {nhx, nhy, nhz, nhx, nhy, nhz, nlx, nly};
    const v8h A1 = {nlz, one, one, sh, sl, zz, zz, zz};
    const v8h B0 = {hx, hy, hz, lx, ly, lz, hx, hy};
    const v8h B1 = {hz, sh, sl, one, one, zz, zz, zz};

    base[0 * (size_t)n + pi] = __builtin_bit_cast(uint4, A0);
    base[1 * (size_t)n + pi] = __builtin_bit_cast(uint4, A1);
    base[2 * (size_t)n + pi] = __builtin_bit_cast(uint4, B0);
    base[3 * (size_t)n + pi] = __builtin_bit_cast(uint4, B1);
}

__global__ __launch_bounds__(TPB)
__attribute__((amdgpu_waves_per_eu(4, 4)))
void nnd_mfma_stream(
    const uint4* __restrict__ ws, float* __restrict__ out, int B, int N, int M)
{
    const int dir = blockIdx.z >> 1;     // 0: q=p1,r=p2 (dist1); 1: swapped
    const int s   = blockIdx.z & 1;      // ref-dim split index
    const int b   = blockIdx.y;
    const size_t n1 = (size_t)B * N, n2 = (size_t)B * M;
    const size_t o2 = 4 * n1;

    size_t Ab, Astr, Bb, Bstr;
    int Nq, Nr;
    float* o;
    if (dir == 0) { Ab = 0;  Astr = n1; Bb = o2 + 2 * n2; Bstr = n2; o = out;      Nq = N; Nr = M; }
    else          { Ab = o2; Astr = n2; Bb = 2 * n1;      Bstr = n1; o = out + n1; Nq = M; Nr = N; }

    const int tid  = threadIdx.x;
    const int w    = tid >> 6;
    const int lane = tid & 63;
    const int c    = lane & 31;          // MFMA row (A) / col (B) within tile
    const int g    = lane >> 5;          // k-half
    const int row0 = blockIdx.x * RPB + w * RPW;

    const uint4* Ag = ws + Ab + (size_t)g * Astr + (size_t)b * Nq;
    const uint4* Bg = ws + Bb + (size_t)g * Bstr + (size_t)b * Nr;

    const v8h a0 = __builtin_bit_cast(v8h, Ag[row0 + c]);
    const v8h a1 = __builtin_bit_cast(v8h, Ag[row0 + 32 + c]);

    v16f zc;
#pragma unroll
    for (int i = 0; i < 16; ++i) zc[i] = 0.f;
    float rm0[16], rm1[16];
#pragma unroll
    for (int i = 0; i < 16; ++i) { rm0[i] = 3.0e38f; rm1[i] = 3.0e38f; }

    const int r0 = s * (Nr / SPLIT);
    const int r1 = r0 + Nr / SPLIT;

    // barrier-free streaming loop: 4 coalesced 16B loads -> 8 MFMAs -> 64 min3
    for (int j0 = r0; j0 < r1; j0 += 128) {
        const v8h bfA = __builtin_bit_cast(v8h, Bg[j0 + c]);
        const v8h bfB = __builtin_bit_cast(v8h, Bg[j0 + 32 + c]);
        const v8h bfC = __builtin_bit_cast(v8h, Bg[j0 + 64 + c]);
        const v8h bfD = __builtin_bit_cast(v8h, Bg[j0 + 96 + c]);

        const v16f d0a = __builtin_amdgcn_mfma_f32_32x32x16_f16(a0, bfA, zc, 0, 0, 0);
        const v16f d0b = __builtin_amdgcn_mfma_f32_32x32x16_f16(a0, bfB, zc, 0, 0, 0);
        const v16f d1a = __builtin_amdgcn_mfma_f32_32x32x16_f16(a1, bfA, zc, 0, 0, 0);
        const v16f d1b = __builtin_amdgcn_mfma_f32_32x32x16_f16(a1, bfB, zc, 0, 0, 0);
#pragma unroll
        for (int i = 0; i < 16; ++i)
            rm0[i] = fminf(fminf(d0a[i], d0b[i]), rm0[i]);   // v_min3_f32
#pragma unroll
        for (int i = 0; i < 16; ++i)
            rm1[i] = fminf(fminf(d1a[i], d1b[i]), rm1[i]);

        const v16f d0c = __builtin_amdgcn_mfma_f32_32x32x16_f16(a0, bfC, zc, 0, 0, 0);
        const v16f d0d = __builtin_amdgcn_mfma_f32_32x32x16_f16(a0, bfD, zc, 0, 0, 0);
        const v16f d1c = __builtin_amdgcn_mfma_f32_32x32x16_f16(a1, bfC, zc, 0, 0, 0);
        const v16f d1d = __builtin_amdgcn_mfma_f32_32x32x16_f16(a1, bfD, zc, 0, 0, 0);
#pragma unroll
        for (int i = 0; i < 16; ++i)
            rm0[i] = fminf(fminf(d0c[i], d0d[i]), rm0[i]);
#pragma unroll
        for (int i = 0; i < 16; ++i)
            rm1[i] = fminf(fminf(d1c[i], d1d[i]), rm1[i]);
    }

    // min over the 32 columns (bits 0-4); g (bit 5) untouched
#pragma unroll
    for (int i = 0; i < 16; ++i) {
        float v0 = rm0[i], v1 = rm1[i];
        v0 = fminf(v0, __shfl_xor(v0, 1));  v1 = fminf(v1, __shfl_xor(v1, 1));
        v0 = fminf(v0, __shfl_xor(v0, 2));  v1 = fminf(v1, __shfl_xor(v1, 2));
        v0 = fminf(v0, __shfl_xor(v0, 4));  v1 = fminf(v1, __shfl_xor(v1, 4));
        v0 = fminf(v0, __shfl_xor(v0, 8));  v1 = fminf(v1, __shfl_xor(v1, 8));
        v0 = fminf(v0, __shfl_xor(v0, 16)); v1 = fminf(v1, __shfl_xor(v1, 16));
        rm0[i] = v0; rm1[i] = v1;
    }
    if (c == 0) {
#pragma unroll
        for (int i = 0; i < 16; ++i) {
            const int rr = (i & 3) + 8 * (i >> 2) + 4 * g;  // verified C layout
            atomicMin((int*)&o[(size_t)b * Nq + row0 + rr],      __float_as_int(rm0[i]));
            atomicMin((int*)&o[(size_t)b * Nq + row0 + 32 + rr], __float_as_int(rm1[i]));
        }
    }
}

// ---------------- fallback: round-3 identity-folded VALU kernel ----------------
constexpr int FTPB   = 256;
constexpr int FIPT   = 4;
constexpr int FTILE  = 512;
constexpr int FSPLIT = 8;

__global__ __launch_bounds__(FTPB, 4) void nnd_fold(
    const float* __restrict__ p1, const float* __restrict__ p2,
    float* __restrict__ out, int B, int N, int M)
{
    const int z   = blockIdx.z;
    const int dir = z / FSPLIT;
    const int s   = z % FSPLIT;
    const int b   = blockIdx.y;

    const float* __restrict__ q = dir ? p2 : p1;
    const float* __restrict__ r = dir ? p1 : p2;
    const int Nq = dir ? M : N;
    const int Nr = dir ? N : M;
    float* __restrict__ o = out + (dir ? (size_t)B * N : 0) + (size_t)b * Nq;

    const int tid = threadIdx.x;
    const float* qb = q + (size_t)b * Nq * 3;
    float qx[FIPT], qy[FIPT], qz[FIPT], qs[FIPT], mn[FIPT];
    int   qi[FIPT];
#pragma unroll
    for (int i = 0; i < FIPT; ++i) {
        qi[i] = blockIdx.x * (FTPB * FIPT) + i * FTPB + tid;
        if (qi[i] < Nq) {
            qx[i] = qb[qi[i] * 3 + 0]; qy[i] = qb[qi[i] * 3 + 1]; qz[i] = qb[qi[i] * 3 + 2];
        } else { qx[i] = qy[i] = qz[i] = 0.f; }
        float sq = qx[i] * qx[i];
        sq = fmaf(qy[i], qy[i], sq); sq = fmaf(qz[i], qz[i], sq);
        qs[i] = sq; mn[i] = 3.0e38f;
    }
    const int per = (Nr + FSPLIT - 1) / FSPLIT;
    const int r0 = s * per, r1 = min(Nr, r0 + per);
    __shared__ float4 shm[FTILE];
    const float* rb = r + (size_t)b * Nr * 3;
    for (int ts = r0; ts < r1; ts += FTILE) {
        const int npts = min(FTILE, r1 - ts);
        __syncthreads();
        if (npts == FTILE && ((((size_t)b * Nr + (size_t)ts) * 3) & 1) == 0) {
            const float2* src = (const float2*)(rb + (size_t)ts * 3);
            float2 a = src[3 * tid + 0], c2 = src[3 * tid + 1], e = src[3 * tid + 2];
            float s0 = a.x * a.x; s0 = fmaf(a.y, a.y, s0); s0 = fmaf(c2.x, c2.x, s0);
            float s1 = c2.y * c2.y; s1 = fmaf(e.x, e.x, s1); s1 = fmaf(e.y, e.y, s1);
            shm[2 * tid + 0] = make_float4(-2.f * a.x, -2.f * a.y, -2.f * c2.x, s0);
            shm[2 * tid + 1] = make_float4(-2.f * c2.y, -2.f * e.x, -2.f * e.y, s1);
        } else {
#pragma unroll
            for (int k = 0; k < 2; ++k) {
                const int pl = 2 * tid + k;
                float4 v = make_float4(0.f, 0.f, 0.f, 3.0e38f);
                if (pl < npts) {
                    const float* pp = rb + (size_t)(ts + pl) * 3;
                    float sq = pp[0] * pp[0];
                    sq = fmaf(pp[1], pp[1], sq); sq = fmaf(pp[2], pp[2], sq);
                    v = make_float4(-2.f * pp[0], -2.f * pp[1], -2.f * pp[2], sq);
                }
                shm[pl] = v;
            }
        }
        __syncthreads();
#pragma unroll 8
        for (int j = 0; j < FTILE; ++j) {
            const float4 p = shm[j];
#pragma unroll
            for (int i = 0; i < FIPT; ++i) {
                float t = fmaf(p.x, qx[i], p.w);
                t = fmaf(p.y, qy[i], t);
                t = fmaf(p.z, qz[i], t);
                mn[i] = fminf(mn[i], t);
            }
        }
    }
#pragma unroll
    for (int i = 0; i < FIPT; ++i)
        if (qi[i] < Nq) atomicMin((int*)&o[qi[i]], __float_as_int(mn[i] + qs[i]));
}

extern "C" void kernel_launch(void* const* d_in, const int* in_sizes, int n_in,
                              void* d_out, int out_size, void* d_ws, size_t ws_size,
                              hipStream_t stream) {
    const float* p1 = (const float*)d_in[0];
    const float* p2 = (const float*)d_in[1];
    float* out = (float*)d_out;

    const int B = 16;
    const int N = in_sizes[0] / (B * 3);
    const int M = in_sizes[1] / (B * 3);
    const int n1 = B * N, n2 = B * M;
    const size_t need = 64ull * (size_t)(n1 + n2);  // 4 uint4 arrays per set

    // init outputs to large positive float (0x7f7f7f7f ~ 3.39e38) for atomicMin
    hipMemsetAsync(d_out, 0x7f, (size_t)out_size * sizeof(float), stream);

    const bool mfma_ok = (N == M) && (N % RPB == 0) && ((N / SPLIT) % 128 == 0)
                         && (ws_size >= need);

    if (mfma_ok) {
        const int total = n1 + n2;
        pack_pts<<<(total + TPB - 1) / TPB, TPB, 0, stream>>>(p1, p2, (uint4*)d_ws, n1, n2);
        dim3 grid(N / RPB, B, 2 * SPLIT);
        nnd_mfma_stream<<<grid, TPB, 0, stream>>>((const uint4*)d_ws, out, B, N, M);
    } else {
        const int qmax = (N > M) ? N : M;
        dim3 grid((qmax + FTPB * FIPT - 1) / (FTPB * FIPT), B, 2 * FSPLIT);
        nnd_fold<<<grid, FTPB, 0, stream>>>(p1, p2, out, B, N, M);
    }
}

// Round 10
// 42.030 us; speedup vs baseline: 1.1041x; 1.1041x over previous
//
#include <hip/hip_runtime.h>

// Chamfer NN squared distances via MFMA (f16 hi/lo emulation).
// Round-10: 8-waves/SIMD occupancy design (<=64 VGPR loop state).
//
// d(q,r) = |q|^2 + |r|^2 - 2 q.r in ONE mfma_f32_32x32x16_f16 (13 K-slots):
//   A (query row, g=0): {-2hx,-2hy,-2hz,-2hx,-2hy,-2hz,-2lx,-2ly}
//   A (query row, g=1): {-2lz, 1, 1, sh, sl, 0, 0, 0}
//   B (ref col,   g=0): { hx,  hy,  hz,  lx,  ly,  lz, hx, hy}
//   B (ref col,   g=1): { hz,  sh,  sl,  1,  1, 0, 0, 0}
// => D = squared distance (error ~1e-4 vs 0.12 threshold).
//
// R4-R9 lesson: all 4-waves/SIMD variants pin at ~30us = serial pipe sum
// (VALU-min ~10us + DS ~10us + MFMA ~7us) -> latency never hidden. This
// round crosses the VGPR=64 occupancy cliff (m69: waves halve at 64/128):
//   - 1 A-frag/wave (32 rows), single bf/d in flight: zc16+rm16+a4+bf4+d16
//     + addr ~6 = ~62 VGPR, pinned by amdgpu_waves_per_eu(8,8).
//   - B-fragments packed by a separate kernel into d_ws (split-half arrays);
//     staging via global_load_lds width=16: ZERO staging VGPRs/VALU.
//   - CHUNK=512 refs (16 KB LDS) x 8 blocks/CU = 128 KB <= 160.
//   - Grid 2048 blocks (rows 32 x b 16 x dir 2 x SPLIT 2) = 8 blocks/CU
//     = 32 waves/CU. Partial minima combined via atomicMin (262K, 2-way).

typedef _Float16 v8h  __attribute__((ext_vector_type(8)));
typedef float    v16f __attribute__((ext_vector_type(16)));

constexpr int TPB   = 256;        // 4 waves
constexpr int RPW   = 32;         // rows per wave (1 A-fragment)
constexpr int RPB   = 4 * RPW;    // 128 rows per block
constexpr int CHUNK = 512;        // ref points per LDS pass (2 x 8 KB halves)
constexpr int SPLIT = 2;          // ref-dim split factor

__device__ __forceinline__ void split3(float x, float y, float z,
    _Float16& hx, _Float16& hy, _Float16& hz,
    _Float16& lx, _Float16& ly, _Float16& lz,
    _Float16& sh, _Float16& sl)
{
    const float s = fmaf(z, z, fmaf(y, y, x * x));
    hx = (_Float16)x; hy = (_Float16)y; hz = (_Float16)z;
    lx = (_Float16)(x - (float)hx);
    ly = (_Float16)(y - (float)hy);
    lz = (_Float16)(z - (float)hz);
    sh = (_Float16)s;
    sl = (_Float16)(s - (float)sh);
}

// ws layout (uint4 units): per point set, 4 arrays of length n:
//   A_g0 | A_g1 | B_g0 | B_g1   (set1 at 0, set2 at 4*n1)
__global__ void pack_pts(const float* __restrict__ p1, const float* __restrict__ p2,
                         uint4* __restrict__ ws, int n1, int n2)
{
    const int gid = blockIdx.x * blockDim.x + threadIdx.x;
    if (gid >= n1 + n2) return;
    const float* src;
    int pi, n;
    uint4* base;
    if (gid < n1) { src = p1; pi = gid;      n = n1; base = ws; }
    else          { src = p2; pi = gid - n1; n = n2; base = ws + 4 * (size_t)n1; }

    const float x = src[(size_t)pi * 3 + 0];
    const float y = src[(size_t)pi * 3 + 1];
    const float z = src[(size_t)pi * 3 + 2];
    _Float16 hx, hy, hz, lx, ly, lz, sh, sl;
    split3(x, y, z, hx, hy, hz, lx, ly, lz, sh, sl);
    const _Float16 nhx = (_Float16)(-2.f * x);
    const _Float16 nhy = (_Float16)(-2.f * y);
    const _Float16 nhz = (_Float16)(-2.f * z);
    const _Float16 nlx = (_Float16)(-2.f * (float)lx);
    const _Float16 nly = (_Float16)(-2.f * (float)ly);
    const _Float16 nlz = (_Float16)(-2.f * (float)lz);
    const _Float16 one = (_Float16)1.f, zz = (_Float16)0.f;

    const v8h A0 = {nhx, nhy, nhz, nhx, nhy, nhz, nlx, nly};
    const v8h A1 = {nlz, one, one, sh, sl, zz, zz, zz};
    const v8h B0 = {hx, hy, hz, lx, ly, lz, hx, hy};
    const v8h B1 = {hz, sh, sl, one, one, zz, zz, zz};

    base[0 * (size_t)n + pi] = __builtin_bit_cast(uint4, A0);
    base[1 * (size_t)n + pi] = __builtin_bit_cast(uint4, A1);
    base[2 * (size_t)n + pi] = __builtin_bit_cast(uint4, B0);
    base[3 * (size_t)n + pi] = __builtin_bit_cast(uint4, B1);
}

__global__ __launch_bounds__(TPB)
__attribute__((amdgpu_waves_per_eu(8, 8)))
void nnd_mfma8w(
    const uint4* __restrict__ ws, float* __restrict__ out, int B, int N, int M)
{
    const int dir = blockIdx.z >> 1;     // 0: q=p1,r=p2 (dist1); 1: swapped
    const int s   = blockIdx.z & 1;      // ref-dim split index
    const int b   = blockIdx.y;
    const size_t n1 = (size_t)B * N, n2 = (size_t)B * M;

    size_t Ab, Astr, Bb, Bstr;
    int Nq, Nr;
    float* o;
    if (dir == 0) { Ab = 0;      Astr = n1; Bb = 4*n1 + 2*n2; Bstr = n2; o = out;      Nq = N; Nr = M; }
    else          { Ab = 4*n1;   Astr = n2; Bb = 2*n1;        Bstr = n1; o = out + n1; Nq = M; Nr = N; }

    const int tid  = threadIdx.x;
    const int w    = tid >> 6;
    const int lane = tid & 63;
    const int c    = lane & 31;          // MFMA row (A) / col (B) within tile
    const int g    = lane >> 5;          // k-half
    const int row0 = blockIdx.x * RPB + w * RPW;

    // A fragment (per-lane load, once)
    const v8h a0 = __builtin_bit_cast(v8h,
        ws[Ab + (size_t)g * Astr + (size_t)b * Nq + row0 + c]);

    v16f zc;
#pragma unroll
    for (int i = 0; i < 16; ++i) zc[i] = 0.f;
    float rm[16];
#pragma unroll
    for (int i = 0; i < 16; ++i) rm[i] = 3.0e38f;

    __shared__ uint4 sb[2 * CHUNK];      // [half][slot]
    const uint4* Bbase = ws + Bb + (size_t)b * Nr;   // + h*Bstr per half

    const int r0 = s * (Nr / SPLIT);
    const int r1 = r0 + Nr / SPLIT;
    const int wbase = (tid & 192);       // wave's 64-element slot within an issue

    for (int ts = r0; ts < r1; ts += CHUNK) {
        __syncthreads();                 // previous chunk fully consumed
        // stage CHUNK refs x 2 halves via global_load_lds (16 B/lane, linear)
#pragma unroll
        for (int h = 0; h < 2; ++h) {
#pragma unroll
            for (int j = 0; j < CHUNK / TPB; ++j) {
                const uint4* gsrc = Bbase + (size_t)h * Bstr + ts + j * TPB + tid;
                __builtin_amdgcn_global_load_lds(
                    (const __attribute__((address_space(1))) uint4*)gsrc,
                    (__attribute__((address_space(3))) uint4*)&sb[h * CHUNK + j * TPB + wbase],
                    16, 0, 0);
            }
        }
        __syncthreads();                 // drains vmcnt before reads

#pragma unroll 4
        for (int st = 0; st < CHUNK / 32; ++st) {
            const v8h bf = __builtin_bit_cast(v8h, sb[g * CHUNK + st * 32 + c]);
            const v16f d = __builtin_amdgcn_mfma_f32_32x32x16_f16(a0, bf, zc, 0, 0, 0);
#pragma unroll
            for (int i = 0; i < 16; ++i)
                rm[i] = fminf(rm[i], d[i]);
        }
    }

    // min over the 32 columns (bits 0-4); g (bit 5) untouched
#pragma unroll
    for (int i = 0; i < 16; ++i) {
        float v = rm[i];
        v = fminf(v, __shfl_xor(v, 1));
        v = fminf(v, __shfl_xor(v, 2));
        v = fminf(v, __shfl_xor(v, 4));
        v = fminf(v, __shfl_xor(v, 8));
        v = fminf(v, __shfl_xor(v, 16));
        rm[i] = v;
    }
    if (c == 0) {
#pragma unroll
        for (int i = 0; i < 16; ++i) {
            const int rr = (i & 3) + 8 * (i >> 2) + 4 * g;  // verified C layout
            atomicMin((int*)&o[(size_t)b * Nq + row0 + rr], __float_as_int(rm[i]));
        }
    }
}

// ---------------- fallback: round-3 identity-folded VALU kernel ----------------
constexpr int FTPB   = 256;
constexpr int FIPT   = 4;
constexpr int FTILE  = 512;
constexpr int FSPLIT = 8;

__global__ __launch_bounds__(FTPB, 4) void nnd_fold(
    const float* __restrict__ p1, const float* __restrict__ p2,
    float* __restrict__ out, int B, int N, int M)
{
    const int z   = blockIdx.z;
    const int dir = z / FSPLIT;
    const int s   = z % FSPLIT;
    const int b   = blockIdx.y;

    const float* __restrict__ q = dir ? p2 : p1;
    const float* __restrict__ r = dir ? p1 : p2;
    const int Nq = dir ? M : N;
    const int Nr = dir ? N : M;
    float* __restrict__ o = out + (dir ? (size_t)B * N : 0) + (size_t)b * Nq;

    const int tid = threadIdx.x;
    const float* qb = q + (size_t)b * Nq * 3;
    float qx[FIPT], qy[FIPT], qz[FIPT], qs[FIPT], mn[FIPT];
    int   qi[FIPT];
#pragma unroll
    for (int i = 0; i < FIPT; ++i) {
        qi[i] = blockIdx.x * (FTPB * FIPT) + i * FTPB + tid;
        if (qi[i] < Nq) {
            qx[i] = qb[qi[i] * 3 + 0]; qy[i] = qb[qi[i] * 3 + 1]; qz[i] = qb[qi[i] * 3 + 2];
        } else { qx[i] = qy[i] = qz[i] = 0.f; }
        float sq = qx[i] * qx[i];
        sq = fmaf(qy[i], qy[i], sq); sq = fmaf(qz[i], qz[i], sq);
        qs[i] = sq; mn[i] = 3.0e38f;
    }
    const int per = (Nr + FSPLIT - 1) / FSPLIT;
    const int r0 = s * per, r1 = min(Nr, r0 + per);
    __shared__ float4 shm[FTILE];
    const float* rb = r + (size_t)b * Nr * 3;
    for (int ts = r0; ts < r1; ts += FTILE) {
        const int npts = min(FTILE, r1 - ts);
        __syncthreads();
        if (npts == FTILE && ((((size_t)b * Nr + (size_t)ts) * 3) & 1) == 0) {
            const float2* src = (const float2*)(rb + (size_t)ts * 3);
            float2 a = src[3 * tid + 0], c2 = src[3 * tid + 1], e = src[3 * tid + 2];
            float s0 = a.x * a.x; s0 = fmaf(a.y, a.y, s0); s0 = fmaf(c2.x, c2.x, s0);
            float s1 = c2.y * c2.y; s1 = fmaf(e.x, e.x, s1); s1 = fmaf(e.y, e.y, s1);
            shm[2 * tid + 0] = make_float4(-2.f * a.x, -2.f * a.y, -2.f * c2.x, s0);
            shm[2 * tid + 1] = make_float4(-2.f * c2.y, -2.f * e.x, -2.f * e.y, s1);
        } else {
#pragma unroll
            for (int k = 0; k < 2; ++k) {
                const int pl = 2 * tid + k;
                float4 v = make_float4(0.f, 0.f, 0.f, 3.0e38f);
                if (pl < npts) {
                    const float* pp = rb + (size_t)(ts + pl) * 3;
                    float sq = pp[0] * pp[0];
                    sq = fmaf(pp[1], pp[1], sq); sq = fmaf(pp[2], pp[2], sq);
                    v = make_float4(-2.f * pp[0], -2.f * pp[1], -2.f * pp[2], sq);
                }
                shm[pl] = v;
            }
        }
        __syncthreads();
#pragma unroll 8
        for (int j = 0; j < FTILE; ++j) {
            const float4 p = shm[j];
#pragma unroll
            for (int i = 0; i < FIPT; ++i) {
                float t = fmaf(p.x, qx[i], p.w);
                t = fmaf(p.y, qy[i], t);
                t = fmaf(p.z, qz[i], t);
                mn[i] = fminf(mn[i], t);
            }
        }
    }
#pragma unroll
    for (int i = 0; i < FIPT; ++i)
        if (qi[i] < Nq) atomicMin((int*)&o[qi[i]], __float_as_int(mn[i] + qs[i]));
}

extern "C" void kernel_launch(void* const* d_in, const int* in_sizes, int n_in,
                              void* d_out, int out_size, void* d_ws, size_t ws_size,
                              hipStream_t stream) {
    const float* p1 = (const float*)d_in[0];
    const float* p2 = (const float*)d_in[1];
    float* out = (float*)d_out;

    const int B = 16;
    const int N = in_sizes[0] / (B * 3);
    const int M = in_sizes[1] / (B * 3);
    const int n1 = B * N, n2 = B * M;
    const size_t need = 64ull * (size_t)(n1 + n2);  // 4 uint4 arrays per set

    // init outputs to large positive float (0x7f7f7f7f ~ 3.39e38) for atomicMin
    hipMemsetAsync(d_out, 0x7f, (size_t)out_size * sizeof(float), stream);

    const bool mfma_ok = (N == M) && (N % RPB == 0) && ((N / SPLIT) % CHUNK == 0)
                         && (ws_size >= need);

    if (mfma_ok) {
        const int total = n1 + n2;
        pack_pts<<<(total + TPB - 1) / TPB, TPB, 0, stream>>>(p1, p2, (uint4*)d_ws, n1, n2);
        dim3 grid(N / RPB, B, 2 * SPLIT);
        nnd_mfma8w<<<grid, TPB, 0, stream>>>((const uint4*)d_ws, out, B, N, M);
    } else {
        const int qmax = (N > M) ? N : M;
        dim3 grid((qmax + FTPB * FIPT - 1) / (FTPB * FIPT), B, 2 * FSPLIT);
        nnd_fold<<<grid, FTPB, 0, stream>>>(p1, p2, out, B, N, M);
    }
}

// Round 11
// 28.532 us; speedup vs baseline: 1.6263x; 1.4731x over previous
//
#include <hip/hip_runtime.h>

// Chamfer NN squared distances via MFMA (f16 hi/lo emulation).
// Round-11: SINGLE-DISPATCH kernel (no memset, no atomics, no pack kernel,
// no workspace) with 2-phase pipelined staging (T14 split).
//
// d(q,r) = |q|^2 + |r|^2 - 2 q.r in ONE mfma_f32_32x32x16_f16 (13 K-slots):
//   A (query row, g=0): {-2hx,-2hy,-2hz,-2hx,-2hy,-2hz,-2lx,-2ly}
//   A (query row, g=1): {-2lz, 1, 1, sh, sl, 0, 0, 0}
//   B (ref col,   g=0): { hx,  hy,  hz,  lx,  ly,  lz, hx, hy}
//   B (ref col,   g=1): { hz,  sh,  sl,  1,  1, 0, 0, 0}
// => D = squared distance (error ~1e-4 vs 0.12 threshold).
//
// Structure: each wave owns 32 query rows (1 A-frag) and sweeps ALL refs ->
// complete min -> DIRECT STORE (no memset/atomicMin). Grid 1024 blocks
// (32 row-blocks x 16 batches x 2 dirs) = 4 blocks/CU, 4 waves/SIMD.
// Per chunk (512 refs, double-buffered 2x16KB LDS):
//   issue global loads (t+1) -> compute buf[cur] -> pack+ds_write buf[cur^1]
//   -> barrier.  Loads fly under compute (T14); one barrier/chunk.
// Inner pair-step: 2 ds_read_b128 (consecutive, conflict-free), 2 MFMA,
// 16 v_min3 (fold both d's into rm) = 20 instr / 2048 pairs.

typedef _Float16 v8h  __attribute__((ext_vector_type(8)));
typedef float    v16f __attribute__((ext_vector_type(16)));

constexpr int TPB   = 256;        // 4 waves
constexpr int RPW   = 32;         // rows per wave (1 A-fragment)
constexpr int RPB   = 4 * RPW;    // 128 rows per block
constexpr int CHUNK = 512;        // refs per buffer (2 halves x 8 KB)

__device__ __forceinline__ void split3(float x, float y, float z,
    _Float16& hx, _Float16& hy, _Float16& hz,
    _Float16& lx, _Float16& ly, _Float16& lz,
    _Float16& sh, _Float16& sl)
{
    const float s = fmaf(z, z, fmaf(y, y, x * x));
    hx = (_Float16)x; hy = (_Float16)y; hz = (_Float16)z;
    lx = (_Float16)(x - (float)hx);
    ly = (_Float16)(y - (float)hy);
    lz = (_Float16)(z - (float)hz);
    sh = (_Float16)s;
    sl = (_Float16)(s - (float)sh);
}

__device__ __forceinline__ v8h packA(const float* __restrict__ qb, int row, int g)
{
    const float x = qb[(size_t)row * 3 + 0];
    const float y = qb[(size_t)row * 3 + 1];
    const float z = qb[(size_t)row * 3 + 2];
    _Float16 hx, hy, hz, lx, ly, lz, sh, sl;
    split3(x, y, z, hx, hy, hz, lx, ly, lz, sh, sl);
    const _Float16 nhx = (_Float16)(-2.f * x);
    const _Float16 nhy = (_Float16)(-2.f * y);
    const _Float16 nhz = (_Float16)(-2.f * z);
    const _Float16 nlx = (_Float16)(-2.f * (float)lx);
    const _Float16 nly = (_Float16)(-2.f * (float)ly);
    const _Float16 nlz = (_Float16)(-2.f * (float)lz);
    const _Float16 one = (_Float16)1.f, zz = (_Float16)0.f;
    const v8h A0 = {nhx, nhy, nhz, nhx, nhy, nhz, nlx, nly};
    const v8h A1 = {nlz, one, one, sh, sl, zz, zz, zz};
    return g ? A1 : A0;
}

__device__ __forceinline__ void packB(float x, float y, float z, uint4& h0, uint4& h1)
{
    _Float16 hx, hy, hz, lx, ly, lz, sh, sl;
    split3(x, y, z, hx, hy, hz, lx, ly, lz, sh, sl);
    const _Float16 one = (_Float16)1.f, zz = (_Float16)0.f;
    const v8h B0 = {hx, hy, hz, lx, ly, lz, hx, hy};
    const v8h B1 = {hz, sh, sl, one, one, zz, zz, zz};
    h0 = __builtin_bit_cast(uint4, B0);
    h1 = __builtin_bit_cast(uint4, B1);
}

__global__ __launch_bounds__(TPB)
__attribute__((amdgpu_waves_per_eu(4, 4)))
void nnd_mfma5(
    const float* __restrict__ p1, const float* __restrict__ p2,
    float* __restrict__ out, int B, int N, int M)
{
    const int dir = blockIdx.z;          // 0: q=p1,r=p2 (dist1); 1: swapped
    const int b   = blockIdx.y;
    const float* __restrict__ q = dir ? p2 : p1;
    const float* __restrict__ r = dir ? p1 : p2;
    const int Nq = dir ? M : N;
    const int Nr = dir ? N : M;
    float* __restrict__ o = out + (dir ? (size_t)B * N : 0) + (size_t)b * Nq;

    const int tid  = threadIdx.x;
    const int w    = tid >> 6;
    const int lane = tid & 63;
    const int c    = lane & 31;          // MFMA row (A) / col (B) within tile
    const int g    = lane >> 5;          // k-half
    const int row0 = blockIdx.x * RPB + w * RPW;

    const float* qb = q + (size_t)b * Nq * 3;
    const v8h a = packA(qb, row0 + c, g);

    v16f zc;
#pragma unroll
    for (int i = 0; i < 16; ++i) zc[i] = 0.f;
    float rm[16];
#pragma unroll
    for (int i = 0; i < 16; ++i) rm[i] = 3.0e38f;

    __shared__ uint4 sb[2][2 * CHUNK];   // [buf][half*CHUNK + slot]
    const float* rb = r + (size_t)b * Nr * 3;

    // ---- prologue: stage chunk 0 into buf 0 ----
    {
        const float2* s2 = (const float2*)rb;
        const float2 A  = s2[3 * tid + 0];
        const float2 C2 = s2[3 * tid + 1];
        const float2 E  = s2[3 * tid + 2];
        uint4 h00, h01, h10, h11;
        packB(A.x, A.y, C2.x, h00, h01);
        packB(C2.y, E.x, E.y, h10, h11);
        sb[0][tid]               = h00;
        sb[0][TPB + tid]         = h10;
        sb[0][CHUNK + tid]       = h01;
        sb[0][CHUNK + TPB + tid] = h11;
    }
    __syncthreads();

    const int NT = Nr / CHUNK;
    int cur = 0;
    for (int t = 0; t < NT; ++t) {
        const bool more = (t + 1 < NT);
        // (1) issue global loads for chunk t+1 (fly under compute)
        float2 A, C2, E;
        if (more) {
            const float2* s2 = (const float2*)(rb + (size_t)(t + 1) * CHUNK * 3);
            A  = s2[3 * tid + 0];
            C2 = s2[3 * tid + 1];
            E  = s2[3 * tid + 2];
        }
        // (2) compute on buf[cur]: 8 pair-steps (2 ds_read, 2 MFMA, 16 min3)
        const uint4* sbase = &sb[cur][g * CHUNK];
#pragma unroll 2
        for (int st = 0; st < CHUNK / 32; st += 2) {
            const v8h bfA = __builtin_bit_cast(v8h, sbase[st * 32 + c]);
            const v8h bfB = __builtin_bit_cast(v8h, sbase[st * 32 + 32 + c]);
            const v16f da = __builtin_amdgcn_mfma_f32_32x32x16_f16(a, bfA, zc, 0, 0, 0);
            const v16f db = __builtin_amdgcn_mfma_f32_32x32x16_f16(a, bfB, zc, 0, 0, 0);
#pragma unroll
            for (int i = 0; i < 16; ++i)
                rm[i] = fminf(fminf(da[i], db[i]), rm[i]);   // v_min3_f32
        }
        // (3) pack + write chunk t+1 into buf[cur^1]
        if (more) {
            uint4 h00, h01, h10, h11;
            packB(A.x, A.y, C2.x, h00, h01);
            packB(C2.y, E.x, E.y, h10, h11);
            uint4* d = sb[cur ^ 1];
            d[tid]               = h00;
            d[TPB + tid]         = h10;
            d[CHUNK + tid]       = h01;
            d[CHUNK + TPB + tid] = h11;
            __syncthreads();             // writes visible before next compute
        }
        cur ^= 1;
    }

    // ---- epilogue: min over the 32 columns (bits 0-4), direct store ----
#pragma unroll
    for (int i = 0; i < 16; ++i) {
        float v = rm[i];
        v = fminf(v, __shfl_xor(v, 1));
        v = fminf(v, __shfl_xor(v, 2));
        v = fminf(v, __shfl_xor(v, 4));
        v = fminf(v, __shfl_xor(v, 8));
        v = fminf(v, __shfl_xor(v, 16));
        rm[i] = v;
    }
    if (c == 0) {
#pragma unroll
        for (int i = 0; i < 16; ++i) {
            const int rr = (i & 3) + 8 * (i >> 2) + 4 * g;  // verified C layout
            o[row0 + rr] = rm[i];
        }
    }
}

// ---------------- fallback: round-3 identity-folded VALU kernel ----------------
constexpr int FTPB   = 256;
constexpr int FIPT   = 4;
constexpr int FTILE  = 512;
constexpr int FSPLIT = 8;

__global__ __launch_bounds__(FTPB, 4) void nnd_fold(
    const float* __restrict__ p1, const float* __restrict__ p2,
    float* __restrict__ out, int B, int N, int M)
{
    const int z   = blockIdx.z;
    const int dir = z / FSPLIT;
    const int s   = z % FSPLIT;
    const int b   = blockIdx.y;

    const float* __restrict__ q = dir ? p2 : p1;
    const float* __restrict__ r = dir ? p1 : p2;
    const int Nq = dir ? M : N;
    const int Nr = dir ? N : M;
    float* __restrict__ o = out + (dir ? (size_t)B * N : 0) + (size_t)b * Nq;

    const int tid = threadIdx.x;
    const float* qb = q + (size_t)b * Nq * 3;
    float qx[FIPT], qy[FIPT], qz[FIPT], qs[FIPT], mn[FIPT];
    int   qi[FIPT];
#pragma unroll
    for (int i = 0; i < FIPT; ++i) {
        qi[i] = blockIdx.x * (FTPB * FIPT) + i * FTPB + tid;
        if (qi[i] < Nq) {
            qx[i] = qb[qi[i] * 3 + 0]; qy[i] = qb[qi[i] * 3 + 1]; qz[i] = qb[qi[i] * 3 + 2];
        } else { qx[i] = qy[i] = qz[i] = 0.f; }
        float sq = qx[i] * qx[i];
        sq = fmaf(qy[i], qy[i], sq); sq = fmaf(qz[i], qz[i], sq);
        qs[i] = sq; mn[i] = 3.0e38f;
    }
    const int per = (Nr + FSPLIT - 1) / FSPLIT;
    const int r0 = s * per, r1 = min(Nr, r0 + per);
    __shared__ float4 shm[FTILE];
    const float* rb = r + (size_t)b * Nr * 3;
    for (int ts = r0; ts < r1; ts += FTILE) {
        const int npts = min(FTILE, r1 - ts);
        __syncthreads();
        if (npts == FTILE && ((((size_t)b * Nr + (size_t)ts) * 3) & 1) == 0) {
            const float2* src = (const float2*)(rb + (size_t)ts * 3);
            float2 a = src[3 * tid + 0], c2 = src[3 * tid + 1], e = src[3 * tid + 2];
            float s0 = a.x * a.x; s0 = fmaf(a.y, a.y, s0); s0 = fmaf(c2.x, c2.x, s0);
            float s1 = c2.y * c2.y; s1 = fmaf(e.x, e.x, s1); s1 = fmaf(e.y, e.y, s1);
            shm[2 * tid + 0] = make_float4(-2.f * a.x, -2.f * a.y, -2.f * c2.x, s0);
            shm[2 * tid + 1] = make_float4(-2.f * c2.y, -2.f * e.x, -2.f * e.y, s1);
        } else {
#pragma unroll
            for (int k = 0; k < 2; ++k) {
                const int pl = 2 * tid + k;
                float4 v = make_float4(0.f, 0.f, 0.f, 3.0e38f);
                if (pl < npts) {
                    const float* pp = rb + (size_t)(ts + pl) * 3;
                    float sq = pp[0] * pp[0];
                    sq = fmaf(pp[1], pp[1], sq); sq = fmaf(pp[2], pp[2], sq);
                    v = make_float4(-2.f * pp[0], -2.f * pp[1], -2.f * pp[2], sq);
                }
                shm[pl] = v;
            }
        }
        __syncthreads();
#pragma unroll 8
        for (int j = 0; j < FTILE; ++j) {
            const float4 p = shm[j];
#pragma unroll
            for (int i = 0; i < FIPT; ++i) {
                float t = fmaf(p.x, qx[i], p.w);
                t = fmaf(p.y, qy[i], t);
                t = fmaf(p.z, qz[i], t);
                mn[i] = fminf(mn[i], t);
            }
        }
    }
#pragma unroll
    for (int i = 0; i < FIPT; ++i)
        if (qi[i] < Nq) atomicMin((int*)&o[qi[i]], __float_as_int(mn[i] + qs[i]));
}

extern "C" void kernel_launch(void* const* d_in, const int* in_sizes, int n_in,
                              void* d_out, int out_size, void* d_ws, size_t ws_size,
                              hipStream_t stream) {
    const float* p1 = (const float*)d_in[0];
    const float* p2 = (const float*)d_in[1];
    float* out = (float*)d_out;

    const int B = 16;
    const int N = in_sizes[0] / (B * 3);
    const int M = in_sizes[1] / (B * 3);

    const bool mfma_ok = (N == M) && (N % RPB == 0) && (N % CHUNK == 0);

    if (mfma_ok) {
        // single dispatch: direct stores cover every output element
        dim3 grid(N / RPB, B, 2);
        nnd_mfma5<<<grid, TPB, 0, stream>>>(p1, p2, out, B, N, M);
    } else {
        hipMemsetAsync(d_out, 0x7f, (size_t)out_size * sizeof(float), stream);
        const int qmax = (N > M) ? N : M;
        dim3 grid((qmax + FTPB * FIPT - 1) / (FTPB * FIPT), B, 2 * FSPLIT);
        nnd_fold<<<grid, FTPB, 0, stream>>>(p1, p2, out, B, N, M);
    }
}